// Round 10
// baseline (6179.841 us; speedup 1.0000x reference)
//
#include <hip/hip_runtime.h>

// Problem constants
#define Tt    1024
#define INF   256
#define Hh    768
#define OUTF  128

// R10 = R9 (proven 6174us) UNCHANGED + 128 heater WGs (role 3) as a DVFS
// probe: dense register-only VALU FMA to raise chip utilization ~3%->~50%.
// Cycle math says effective clock during R0/R9 was ~200-500 MHz (MfmaUtil
// 13x above the 2.4 GHz model); heaters test (and if right, fix) that.
// Heaters exit when LIN's progress line hits Tt+1. Co-residency by capacity:
// 226 WGs x 16 waves < 8192 slots; 2 x 49.7 KB LDS < 160 KB/CU -> no deadlock.
#define NWG_L0  48
#define NWG_L1  48
#define NWG_LIN 2
#define NWG     (NWG_L0 + NWG_L1 + NWG_LIN)   // 98 (algorithm WGs)
#define NWG_HEAT 128
#define NWG_TOT (NWG + NWG_HEAT)              // 226
#define NTHR    1024

typedef unsigned int       u32;
typedef unsigned long long u64;
typedef unsigned short     u16;
typedef __attribute__((ext_vector_type(8))) short bf16x8;   // 8 bf16 = 4 VGPRs
typedef __attribute__((ext_vector_type(4))) float f32x4;    // MFMA C/D

// ws layout (bytes). prog[wg]: PRIVATE 128-B line, 1 writer, N pollers.
#define PROG_OFF 0                    // 98 lines x 128 B
#define HA_OFF   16384                // hA ring: [3 parity][32 b][768 j] bf16
#define HB_OFF   (HA_OFF + 3*49152)   // hB ring: same
#define WS_BYTES (HB_OFF + 3*49152)   // 311,296 B
#define HPS      24576                // parity stride in u16 (32*768)

#define ASTR_B 1552        // act LDS row stride bytes (776 bf16)
#define RSLAB  272         // red slab stride (dw)
#define RROW   17          // red row stride (dw)

__device__ __forceinline__ float sigf(float v){ return 1.0f/(1.0f+__expf(-v)); }
__device__ __forceinline__ float tanhfast(float x){
    const float cx = fminf(fmaxf(x, -15.f), 15.f);
    const float e  = __expf(2.f * cx);
    return (e - 1.f) / (e + 1.f);
}
__device__ __forceinline__ u16 f2bf(float f){           // round-nearest-even
    u32 u = __float_as_uint(f);
    return (u16)((u + 0x7fffu + ((u>>16)&1u)) >> 16);
}
// LLC-coherent (L1/L2-bypassing) accesses for cross-WG data.
__device__ __forceinline__ void st32ws(u16* p, u32 v){
    __hip_atomic_store((u32*)p, v, __ATOMIC_RELAXED, __HIP_MEMORY_SCOPE_AGENT);
}
__device__ __forceinline__ u32 ldu32(const u32* p){
    return __hip_atomic_load(p, __ATOMIC_RELAXED, __HIP_MEMORY_SCOPE_AGENT);
}
__device__ __forceinline__ void stu32(u32* p, u32 v){
    __hip_atomic_store(p, v, __ATOMIC_RELAXED, __HIP_MEMORY_SCOPE_AGENT);
}
// 16-B cache-bypassing loads, batched, single vmcnt drain inside ONE asm block.
__device__ __forceinline__ void ld16x3(const u16* p0, const u16* p1, const u16* p2,
                                       f32x4& r0, f32x4& r1, f32x4& r2){
    asm volatile(
        "global_load_dwordx4 %0, %3, off sc0 sc1\n\t"
        "global_load_dwordx4 %1, %4, off sc0 sc1\n\t"
        "global_load_dwordx4 %2, %5, off sc0 sc1\n\t"
        "s_waitcnt vmcnt(0)"
        : "=&v"(r0), "=&v"(r1), "=&v"(r2)
        : "v"(p0), "v"(p1), "v"(p2)
        : "memory");
}
__device__ __forceinline__ void ld16x6(const u16* p0, const u16* p1, const u16* p2,
                                       const u16* p3, const u16* p4, const u16* p5,
                                       f32x4& r0, f32x4& r1, f32x4& r2,
                                       f32x4& r3, f32x4& r4, f32x4& r5){
    asm volatile(
        "global_load_dwordx4 %0, %6, off sc0 sc1\n\t"
        "global_load_dwordx4 %1, %7, off sc0 sc1\n\t"
        "global_load_dwordx4 %2, %8, off sc0 sc1\n\t"
        "global_load_dwordx4 %3, %9, off sc0 sc1\n\t"
        "global_load_dwordx4 %4, %10, off sc0 sc1\n\t"
        "global_load_dwordx4 %5, %11, off sc0 sc1\n\t"
        "s_waitcnt vmcnt(0)"
        : "=&v"(r0), "=&v"(r1), "=&v"(r2), "=&v"(r3), "=&v"(r4), "=&v"(r5)
        : "v"(p0), "v"(p1), "v"(p2), "v"(p3), "v"(p4), "v"(p5)
        : "memory");
}

// Gang-poll cnt lines [base, base+cnt) for prog >= thr. Wave 0 only. BUSY.
__device__ __forceinline__ void waitlines(u32* prog, int base, int cnt, u32 thr, int lane){
    bool ok = (lane >= cnt);
    int guard = 0;
    while (guard < (1 << 24)) {
        if (!ok) ok = (ldu32(prog + (base + lane) * 32) >= thr);
        if (__ballot(ok) == ~0ull) break;
        ++guard;
    }
}

__global__ void prologue(char* ws){
    int i = blockIdx.x * 256 + threadIdx.x;
    if (i < WS_BYTES / 4)
        __hip_atomic_store(((u32*)ws) + i, 0u, __ATOMIC_RELAXED, __HIP_MEMORY_SCOPE_AGENT);
}

__device__ __forceinline__ bf16x8 load8w(const float* p){
    float4 v0 = *(const float4*)(p);
    float4 v1 = *(const float4*)(p + 4);
    bf16x8 r;
    r[0]=(short)f2bf(v0.x); r[1]=(short)f2bf(v0.y); r[2]=(short)f2bf(v0.z); r[3]=(short)f2bf(v0.w);
    r[4]=(short)f2bf(v1.x); r[5]=(short)f2bf(v1.y); r[6]=(short)f2bf(v1.z); r[7]=(short)f2bf(v1.w);
    return r;
}

__global__ __launch_bounds__(NTHR) void lstm_persist(
    const float* __restrict__ x,
    const float* __restrict__ Wih0, const float* __restrict__ Whh0,
    const float* __restrict__ bih0, const float* __restrict__ bhh0,
    const float* __restrict__ Wih1, const float* __restrict__ Whh1,
    const float* __restrict__ bih1, const float* __restrict__ bhh1,
    const float* __restrict__ Wlin, const float* __restrict__ blin,
    float* __restrict__ out, char* ws)
{
    u32* prog = (u32*)(ws + PROG_OFF);
    u16* hA   = (u16*)(ws + HA_OFF);
    u16* hB   = (u16*)(ws + HB_OFF);

    const int wg  = blockIdx.x;
    const int tid = threadIdx.x;

    // ---- role 3: DVFS heater. Register-only FMA; exits on LIN's flag. ----
    if (wg >= NWG) {
        const u32* exitp = prog + 96 * 32;           // LIN wg96 progress line
        float a0 = 1.0f + tid * 1e-6f, a1 = 1.1f, a2 = 1.2f, a3 = 1.3f;
        float a4 = 1.4f, a5 = 1.5f, a6 = 1.6f, a7 = 1.7f;
        const float m = 1.0000002f, c = 1.1920929e-7f;
        int guard = 0;
        while (guard < (1 << 20)) {
            #pragma unroll
            for (int i = 0; i < 64; ++i) {
                a0 = __builtin_fmaf(a0, m, c); a1 = __builtin_fmaf(a1, m, c);
                a2 = __builtin_fmaf(a2, m, c); a3 = __builtin_fmaf(a3, m, c);
                a4 = __builtin_fmaf(a4, m, c); a5 = __builtin_fmaf(a5, m, c);
                a6 = __builtin_fmaf(a6, m, c); a7 = __builtin_fmaf(a7, m, c);
            }
            if (ldu32(exitp) >= (u32)(Tt + 1)) break;
            ++guard;
        }
        asm volatile("" :: "v"(a0), "v"(a1), "v"(a2), "v"(a3),
                           "v"(a4), "v"(a5), "v"(a6), "v"(a7));
        return;
    }

    __shared__ __align__(16) char smem[49664];
    char*  actb = smem;                 // [32 b][776 bf16] staging (per chunk)
    float* red  = (float*)smem;         // padded slabs; aliases act after MFMAs

    const int lane = tid & 63, w = tid >> 6;
    const int quad = lane >> 4, nl = lane & 15;
    const int nt = w >> 2, ks = w & 3;          // n-tile 0..3, K-slice 0..3
    const int b3 = tid >> 5, q = tid & 31;      // staging map: batch row, col-block

    const int role  = (wg < NWG_L0) ? 0 : ((wg < NWG_L0 + NWG_L1) ? 1 : 2);
    const int jbase = (role == 0) ? wg * 16 : ((role == 1) ? (wg - NWG_L0) * 16 : 0);
    const int obase = (role == 2) ? (wg - NWG_L0 - NWG_L1) * 64 : 0;

    // ---- register-resident bf16 weights (B-frags), loaded ONCE ----
    // B-frag layout: n = lane&15, k = quad*8 + j.
    bf16x8 bfr[12];
    if (role == 0) {
        const int grow = nt * Hh + jbase + nl;
        #pragma unroll
        for (int fi = 0; fi < 8; ++fi) {
            const int c = fi >> 2, fc = fi & 3;
            const int ka = c * 512 + ks * 128 + fc * 32 + quad * 8;   // K: [x(256); hA(768)]
            const float* p = (ka < 256) ? (Wih0 + (size_t)grow * 256 + ka)
                                        : (Whh0 + (size_t)grow * 768 + (ka - 256));
            bfr[fi] = load8w(p);
        }
    } else if (role == 1) {
        const int grow = nt * Hh + jbase + nl;
        #pragma unroll
        for (int fi = 0; fi < 12; ++fi) {
            const int c = fi / 6, fc = fi % 6;
            const int ka = c * 768 + ks * 192 + fc * 32 + quad * 8;   // K: [hA; hB]
            const float* p = (ka < 768) ? (Wih1 + (size_t)grow * 768 + ka)
                                        : (Whh1 + (size_t)grow * 768 + (ka - 768));
            bfr[fi] = load8w(p);
        }
    } else {
        const int row = obase + nt * 16 + nl;
        #pragma unroll
        for (int fi = 0; fi < 6; ++fi) {
            const int ka = ks * 192 + fi * 32 + quad * 8;
            bfr[fi] = load8w(Wlin + (size_t)row * 768 + ka);
        }
    }

    // gate-thread constants: tid<256 owns (jj, b2) -> j-pair {2jj, 2jj+1}; c in regs
    float ba0=0,ba1=0,ba2=0,ba3=0, bb0=0,bb1=0,bb2=0,bb3=0, creg0=0, creg1=0;
    float bl0 = 0.f, bl1 = 0.f;
    if (role < 2 && tid < 256) {
        const int jg0 = jbase + 2 * (tid >> 5), jg1 = jg0 + 1;
        const float* bi = (role == 0) ? bih0 : bih1;
        const float* bh = (role == 0) ? bhh0 : bhh1;
        ba0 = bi[jg0]        + bh[jg0];        bb0 = bi[jg1]        + bh[jg1];
        ba1 = bi[768 + jg0]  + bh[768 + jg0];  bb1 = bi[768 + jg1]  + bh[768 + jg1];
        ba2 = bi[1536 + jg0] + bh[1536 + jg0]; bb2 = bi[1536 + jg1] + bh[1536 + jg1];
        ba3 = bi[2304 + jg0] + bh[2304 + jg0]; bb3 = bi[2304 + jg1] + bh[2304 + jg1];
    }
    if (role == 2) {
        bl0 = blin[obase + (tid >> 5)];
        bl1 = blin[obase + 32 + (tid >> 5)];
    }

    for (int s = 0; s < Tt + 2; ++s) {
        const bool active = (role == 0) ? (s < Tt)
                          : (role == 1) ? (s >= 1 && s <= Tt)
                          :               (s >= 2);
        const int par_wA = s % 3;              // hA@s      (L0 write)
        const int par_rA = (s + 2) % 3;        // hA@(s-1)  (L0/L1 read)
        const int par_wB = (s + 2) % 3;        // hB@(s-1)  (L1 write)
        const int par_rB = (s + 1) % 3;        // hB@(s-2)  (L1/LIN read)

        // ---- direct dependency polling (wave 0 gang-polls producer lines) ----
        if (active && w == 0) {
            if (role == 0) {
                if (s >= 1) waitlines(prog, 0, 48, (u32)s, lane);            // own: L0 fin s-1
                if (s >= 2) waitlines(prog, 48, 48, (u32)(s - 1), lane);     // WAR: L1 fin s-2
            } else if (role == 1) {
                waitlines(prog, 48, 48, (u32)s, lane);                       // own: L1 fin s-1
                {   // merged: L0 fin s-1 (lanes 0..47) + LIN fin s-2 (lanes 48..49)
                    const u32 thr2 = (lane < 48) ? (u32)s : (u32)(s - 1);
                    const int idx  = (lane < 48) ? lane : (96 + (lane - 48));
                    bool ok = (lane >= 50);
                    int guard = 0;
                    while (guard < (1 << 24)) {
                        if (!ok) ok = (ldu32(prog + idx * 32) >= thr2);
                        if (__ballot(ok) == ~0ull) break;
                        ++guard;
                    }
                }
            } else {
                waitlines(prog, 48, 48, (u32)s, lane);                       // L1 fin s-1
            }
        }
        __syncthreads();

        if (active) {
            f32x4 acc0 = {0.f,0.f,0.f,0.f}, acc1 = {0.f,0.f,0.f,0.f};

            if (role == 0) {
                const float* xs = x + ((size_t)b3 * Tt + s) * INF + q * 8;
                const float4 v0 = *(const float4*)xs;
                const float4 v1 = *(const float4*)(xs + 4);
                const u16* hp = hA + (size_t)par_rA * HPS + b3 * 768;
                f32x4 h0, h1, h2;
                ld16x3(hp + q * 8, hp + 256 + q * 8, hp + 512 + q * 8, h0, h1, h2);
                // chunk 0: cols [0,256)=x(t) bf16, [256,512)=hA[0,256)
                {
                    uint4 xv;
                    xv.x = (u32)f2bf(v0.x) | ((u32)f2bf(v0.y) << 16);
                    xv.y = (u32)f2bf(v0.z) | ((u32)f2bf(v0.w) << 16);
                    xv.z = (u32)f2bf(v1.x) | ((u32)f2bf(v1.y) << 16);
                    xv.w = (u32)f2bf(v1.z) | ((u32)f2bf(v1.w) << 16);
                    *(uint4*)(actb + b3 * ASTR_B + q * 16) = xv;
                    *(f32x4*)(actb + b3 * ASTR_B + 512 + q * 16) = h0;
                }
                __syncthreads();
                #pragma unroll
                for (int fc = 0; fc < 4; ++fc) {
                    const int koff = ks * 128 + fc * 32 + quad * 8;
                    bf16x8 a0 = *(const bf16x8*)(actb + nl * ASTR_B + koff * 2);
                    bf16x8 a1 = *(const bf16x8*)(actb + (16 + nl) * ASTR_B + koff * 2);
                    acc0 = __builtin_amdgcn_mfma_f32_16x16x32_bf16(a0, bfr[fc], acc0, 0, 0, 0);
                    acc1 = __builtin_amdgcn_mfma_f32_16x16x32_bf16(a1, bfr[fc], acc1, 0, 0, 0);
                }
                __syncthreads();
                // chunk 1: cols [0,512) = hA[256,768)
                *(f32x4*)(actb + b3 * ASTR_B + q * 16)       = h1;
                *(f32x4*)(actb + b3 * ASTR_B + 512 + q * 16) = h2;
                __syncthreads();
                #pragma unroll
                for (int fc = 0; fc < 4; ++fc) {
                    const int koff = ks * 128 + fc * 32 + quad * 8;
                    bf16x8 a0 = *(const bf16x8*)(actb + nl * ASTR_B + koff * 2);
                    bf16x8 a1 = *(const bf16x8*)(actb + (16 + nl) * ASTR_B + koff * 2);
                    acc0 = __builtin_amdgcn_mfma_f32_16x16x32_bf16(a0, bfr[4 + fc], acc0, 0, 0, 0);
                    acc1 = __builtin_amdgcn_mfma_f32_16x16x32_bf16(a1, bfr[4 + fc], acc1, 0, 0, 0);
                }
                __syncthreads();
            } else if (role == 1) {
                const u16* pA = hA + (size_t)par_rA * HPS + b3 * 768;
                const u16* pB = hB + (size_t)par_rB * HPS + b3 * 768;
                f32x4 a0, a1, a2, bq0, bq1, bq2;
                ld16x6(pA + q * 8, pA + 256 + q * 8, pA + 512 + q * 8,
                       pB + q * 8, pB + 256 + q * 8, pB + 512 + q * 8,
                       a0, a1, a2, bq0, bq1, bq2);
                // chunk 0 = hA cols [0,768)
                *(f32x4*)(actb + b3 * ASTR_B + q * 16)        = a0;
                *(f32x4*)(actb + b3 * ASTR_B + 512 + q * 16)  = a1;
                *(f32x4*)(actb + b3 * ASTR_B + 1024 + q * 16) = a2;
                __syncthreads();
                #pragma unroll
                for (int fc = 0; fc < 6; ++fc) {
                    const int koff = ks * 192 + fc * 32 + quad * 8;
                    bf16x8 f0 = *(const bf16x8*)(actb + nl * ASTR_B + koff * 2);
                    bf16x8 f1 = *(const bf16x8*)(actb + (16 + nl) * ASTR_B + koff * 2);
                    acc0 = __builtin_amdgcn_mfma_f32_16x16x32_bf16(f0, bfr[fc], acc0, 0, 0, 0);
                    acc1 = __builtin_amdgcn_mfma_f32_16x16x32_bf16(f1, bfr[fc], acc1, 0, 0, 0);
                }
                __syncthreads();
                // chunk 1 = hB cols [0,768)
                *(f32x4*)(actb + b3 * ASTR_B + q * 16)        = bq0;
                *(f32x4*)(actb + b3 * ASTR_B + 512 + q * 16)  = bq1;
                *(f32x4*)(actb + b3 * ASTR_B + 1024 + q * 16) = bq2;
                __syncthreads();
                #pragma unroll
                for (int fc = 0; fc < 6; ++fc) {
                    const int koff = ks * 192 + fc * 32 + quad * 8;
                    bf16x8 f0 = *(const bf16x8*)(actb + nl * ASTR_B + koff * 2);
                    bf16x8 f1 = *(const bf16x8*)(actb + (16 + nl) * ASTR_B + koff * 2);
                    acc0 = __builtin_amdgcn_mfma_f32_16x16x32_bf16(f0, bfr[6 + fc], acc0, 0, 0, 0);
                    acc1 = __builtin_amdgcn_mfma_f32_16x16x32_bf16(f1, bfr[6 + fc], acc1, 0, 0, 0);
                }
                __syncthreads();
            } else {
                const u16* pB = hB + (size_t)par_rB * HPS + b3 * 768;
                f32x4 bq0, bq1, bq2;
                ld16x3(pB + q * 8, pB + 256 + q * 8, pB + 512 + q * 8, bq0, bq1, bq2);
                *(f32x4*)(actb + b3 * ASTR_B + q * 16)        = bq0;
                *(f32x4*)(actb + b3 * ASTR_B + 512 + q * 16)  = bq1;
                *(f32x4*)(actb + b3 * ASTR_B + 1024 + q * 16) = bq2;
                __syncthreads();
                // early WAR release: hB(s-2) reads drained in-block before barrier.
                if (tid == 0) stu32(prog + wg * 32, (u32)(s + 1));
                #pragma unroll
                for (int fc = 0; fc < 6; ++fc) {
                    const int koff = ks * 192 + fc * 32 + quad * 8;
                    bf16x8 f0 = *(const bf16x8*)(actb + nl * ASTR_B + koff * 2);
                    bf16x8 f1 = *(const bf16x8*)(actb + (16 + nl) * ASTR_B + koff * 2);
                    acc0 = __builtin_amdgcn_mfma_f32_16x16x32_bf16(f0, bfr[fc], acc0, 0, 0, 0);
                    acc1 = __builtin_amdgcn_mfma_f32_16x16x32_bf16(f1, bfr[fc], acc1, 0, 0, 0);
                }
                __syncthreads();
            }

            // ---- C tiles -> red (padded; act dead) ----
            // D layout: col n = lane&15, row m = quad*4 + reg.
            *(f32x4*)(red + (size_t)((nt * 2 + 0) * 4 + ks) * RSLAB + nl * RROW + quad * 4) = acc0;
            *(f32x4*)(red + (size_t)((nt * 2 + 1) * 4 + ks) * RSLAB + nl * RROW + quad * 4) = acc1;
            __syncthreads();

            if (role == 2) {
                const int r2 = tid >> 5, bb = tid & 31;
                const int mtr = bb >> 4, mr = bb & 15;
                const int nt0 = r2 >> 4, nr0 = r2 & 15;
                const int nt1 = (r2 + 32) >> 4, nr1 = (r2 + 32) & 15;
                float s0 = 0.f, s1 = 0.f;
                #pragma unroll
                for (int k2 = 0; k2 < 4; ++k2) {
                    s0 += red[(size_t)((nt0 * 2 + mtr) * 4 + k2) * RSLAB + nr0 * RROW + mr];
                    s1 += red[(size_t)((nt1 * 2 + mtr) * 4 + k2) * RSLAB + nr1 * RROW + mr];
                }
                const int v = s - 2;
                float* o = out + ((size_t)bb * Tt + v) * OUTF + obase;
                o[r2]      = s0 + bl0;
                o[32 + r2] = s1 + bl1;
            } else if (tid < 256) {
                // ---- fused K-reduce + gates + direct packed h store ----
                const int jj = tid >> 5, b2 = tid & 31;
                const int mt = b2 >> 4, mr = b2 & 15;
                const int j0 = 2 * jj, j1 = 2 * jj + 1;
                float p0a=0,p1a=0,p2a=0,p3a=0, p0b=0,p1b=0,p2b=0,p3b=0;
                #pragma unroll
                for (int k2 = 0; k2 < 4; ++k2) {
                    p0a += red[(size_t)((0 * 2 + mt) * 4 + k2) * RSLAB + j0 * RROW + mr];
                    p1a += red[(size_t)((1 * 2 + mt) * 4 + k2) * RSLAB + j0 * RROW + mr];
                    p2a += red[(size_t)((2 * 2 + mt) * 4 + k2) * RSLAB + j0 * RROW + mr];
                    p3a += red[(size_t)((3 * 2 + mt) * 4 + k2) * RSLAB + j0 * RROW + mr];
                    p0b += red[(size_t)((0 * 2 + mt) * 4 + k2) * RSLAB + j1 * RROW + mr];
                    p1b += red[(size_t)((1 * 2 + mt) * 4 + k2) * RSLAB + j1 * RROW + mr];
                    p2b += red[(size_t)((2 * 2 + mt) * 4 + k2) * RSLAB + j1 * RROW + mr];
                    p3b += red[(size_t)((3 * 2 + mt) * 4 + k2) * RSLAB + j1 * RROW + mr];
                }
                const float ig0 = sigf(ba0 + p0a), fg0 = sigf(ba1 + p1a);
                const float gv0 = tanhfast(ba2 + p2a), og0 = sigf(ba3 + p3a);
                creg0 = fg0 * creg0 + ig0 * gv0;
                const float h0 = og0 * tanhfast(creg0);
                const float ig1 = sigf(bb0 + p0b), fg1 = sigf(bb1 + p1b);
                const float gv1 = tanhfast(bb2 + p2b), og1 = sigf(bb3 + p3b);
                creg1 = fg1 * creg1 + ig1 * gv1;
                const float h1 = og1 * tanhfast(creg1);
                u16* dst = (role == 0) ? (hA + (size_t)par_wA * HPS)
                                       : (hB + (size_t)par_wB * HPS);
                st32ws(dst + b2 * 768 + jbase + j0, (u32)f2bf(h0) | ((u32)f2bf(h1) << 16));
            }
        }

        // ---- publish progress (barrier drains all stores first) ----
        __syncthreads();
        if (tid == 0) stu32(prog + wg * 32, (u32)(s + 1));
    }
}

extern "C" void kernel_launch(void* const* d_in, const int* in_sizes, int n_in,
                              void* d_out, int out_size, void* d_ws, size_t ws_size,
                              hipStream_t stream)
{
    const float* x    = (const float*)d_in[0];
    const float* Wih0 = (const float*)d_in[1];
    const float* Whh0 = (const float*)d_in[2];
    const float* bih0 = (const float*)d_in[3];
    const float* bhh0 = (const float*)d_in[4];
    const float* Wih1 = (const float*)d_in[5];
    const float* Whh1 = (const float*)d_in[6];
    const float* bih1 = (const float*)d_in[7];
    const float* bhh1 = (const float*)d_in[8];
    const float* Wlin = (const float*)d_in[9];
    const float* blin = (const float*)d_in[10];
    float* out = (float*)d_out;
    char*  ws  = (char*)d_ws;   // uses WS_BYTES = 304 KB

    hipLaunchKernelGGL(prologue, dim3(304), dim3(256), 0, stream, ws);
    hipLaunchKernelGGL(lstm_persist, dim3(NWG_TOT), dim3(NTHR), 0, stream,
                       x, Wih0, Whh0, bih0, bhh0,
                       Wih1, Whh1, bih1, bhh1,
                       Wlin, blin, out, ws);
}